// Round 10
// baseline (3710.286 us; speedup 1.0000x reference)
//
#include <hip/hip_runtime.h>
#include <math.h>

// PEPS amplitude via boundary-MPS contraction, fully fused in one kernel.
// Lx=Ly=10, PHYS=2, D=4, CHI=4. Two teams (2 waves): team0 = bottom half,
// team1 = top half (identical shape sequences -> lockstep barriers).
// Decompositions (MGS-QR, Gram + XOR-scheduled parallel Jacobi) in fp64;
// Jacobi rotation params in fp32 + fp64 Newton orthonormality fix.

#define NS 10

__device__ __forceinline__ double shfl_d(double x, int src) {
  union { double d; int i[2]; } u;
  u.d = x;
  u.i[0] = __shfl(u.i[0], src, 64);
  u.i[1] = __shfl(u.i[1], src, 64);
  return u.d;
}
__device__ __forceinline__ double shflx_d(double x, int m) {
  union { double d; int i[2]; } u;
  u.d = x;
  u.i[0] = __shfl_xor(u.i[0], m, 64);
  u.i[1] = __shfl_xor(u.i[1], m, 64);
  return u.d;
}
__device__ __forceinline__ double wsum64(double x) {
#pragma unroll
  for (int o = 1; o < 64; o <<= 1) x += shflx_d(x, o);
  return x;
}
#define SEL4(a, k) ((k) == 1 ? (a)[1] : (k) == 2 ? (a)[2] : (k) == 3 ? (a)[3] : (a)[0])

// Two-sided parallel Jacobi eigensolver on a zero-padded 16x16 symmetric PSD
// matrix, XOR (hypercube) pair schedule: round d pairs {x, x^d}. Inactive /
// padded pairs self-neutralize (theta=phi=0 -> identity rotation).
// Layout: lane = i*4 + j4 holds G[i][4*j4..4*j4+3] and Vt likewise.
// Rotation (c,s) computed in fp32 (angle error ~1e-7 only slows the tail;
// convergence stays geometric ~1e-7/sweep), then one fp64 Newton step
// enforces c^2+s^2=1 to ~1e-14 so V stays orthogonal.
// No barriers inside (per-team early exit is safe).
template <int NDMAX>
__device__ void jacobi_sym_x(const double* gw, double* vtw, double* ev,
                             int lane, int maxsweep) {
  const int i = lane >> 2, j4 = lane & 3;
  double g[4], v[4];
#pragma unroll
  for (int cc = 0; cc < 4; ++cc) {
    g[cc] = gw[i * 16 + j4 * 4 + cc];
    v[cc] = (i == j4 * 4 + cc) ? 1.0 : 0.0;
  }
  double thr = 0.0;
  for (int sw = 0; sw < maxsweep; ++sw) {
    double off = 0.0, dsq = 0.0;
#pragma unroll
    for (int cc = 0; cc < 4; ++cc) {
      double gv = g[cc];
      if (j4 * 4 + cc == i) dsq += gv * gv; else off += gv * gv;
    }
    if (sw == 0) {
      // trace(G^2) is invariant under the similarity -> compute scale once
      thr = wsum64(off + dsq) * 1e-18;
    } else {
      if (wsum64(off) <= thr) break;  // uniform across wave
    }
#pragma unroll
    for (int d = 1; d <= NDMAX; ++d) {
      const int hb = d >= 8 ? 3 : d >= 4 ? 2 : d >= 2 ? 1 : 0;
      // my row pair {i, i^d}: t1=G[i][i], t2=G[i^d][i^d], t3=G[i][i^d]
      double dsel = SEL4(g, i & 3);                 // provider: G[row][row]
      double psel = SEL4(g, (i & 3) ^ (d & 3));     // provider: G[row][row^d]
      double t1 = shfl_d(dsel, (i << 2) + (i >> 2));
      double t3 = shfl_d(psel, (i << 2) + ((i ^ d) >> 2));
      double t2 = shfl_d(dsel, ((i ^ d) << 2) + ((i ^ d) >> 2));
      bool iq = ((i >> hb) & 1) != 0;               // I'm Q-side of my pair
      double th = iq ? (t1 - t2) : (t2 - t1);       // aqq - app
      double ph = 2.0 * t3;
      // fp32 rotation params (fast) + fp64 Newton orthonormality fix
      float thf = (float)th, phf = (float)ph;
      float denf = fabsf(thf) + sqrtf(thf * thf + phf * phf);
      float tf = (denf > 0.0f) ? copysignf(1.0f, thf) * (phf / denf) : 0.0f;
      float crf = rsqrtf(1.0f + tf * tf);
      double t = (double)tf;
      double c0 = (double)crf;
      double s0 = t * c0;
      double corr = 1.5 - 0.5 * (c0 * c0 + s0 * s0);  // rsqrt Newton near 1
      double cr = c0 * corr;
      double sr = s0 * corr;
      // column phase: col x needs (c,s) of pair {x,x^d} and G[i][x^d]
      double oc[4], os[4], oth[4];
#pragma unroll
      for (int cc = 0; cc < 4; ++cc) {
        int col = (j4 << 2) + cc;
        int asrc = (col << 2) + (col >> 2);         // a lane of row `col`
        oc[cc] = shfl_d(cr, asrc);
        os[cc] = shfl_d(sr, asrc);
        oth[cc] = (d >> 2) ? shflx_d(g[cc ^ (d & 3)], d >> 2)
                           : g[cc ^ (d & 3)];
      }
#pragma unroll
      for (int cc = 0; cc < 4; ++cc) {
        int col = (j4 << 2) + cc;
        double sg = ((col >> hb) & 1) ? os[cc] : -os[cc];  // P side: -s
        g[cc] = oc[cc] * g[cc] + sg * oth[cc];
      }
      // row phase (+ Vt): partner row lane = lane ^ (4d)
      double og[4], ov[4];
#pragma unroll
      for (int cc = 0; cc < 4; ++cc) og[cc] = shflx_d(g[cc], d << 2);
#pragma unroll
      for (int cc = 0; cc < 4; ++cc) ov[cc] = shflx_d(v[cc], d << 2);
      double sg2 = iq ? sr : -sr;
#pragma unroll
      for (int cc = 0; cc < 4; ++cc) {
        g[cc] = cr * g[cc] + sg2 * og[cc];
        v[cc] = cr * v[cc] + sg2 * ov[cc];
      }
    }
  }
#pragma unroll
  for (int cc = 0; cc < 4; ++cc) vtw[i * 16 + j4 * 4 + cc] = v[cc];
  if ((i >> 2) == j4) ev[i] = SEL4(g, i & 3);
}

__global__ __launch_bounds__(128, 1)
void amp_kernel(const float* __restrict__ peps, const int* __restrict__ xs,
                float* __restrict__ out) {
  const int tid = threadIdx.x;
  const int team = tid >> 6;      // 0 = bottom half, 1 = top half
  const int lane = tid & 63;

  __shared__ __align__(16) float Ash[2][NS][1024];  // MPS tensors (l,r,4)
  __shared__ __align__(16) float Tmp[2][1024];      // staging
  __shared__ __align__(16) float Tsh[2][256];       // site tensor T (4,4,4,4)
  __shared__ double Rw[2][256];                     // QR R (16x16)
  __shared__ double Gw[2][256];                     // Gram (16x16, zero-pad)
  __shared__ double Vt[2][256];                     // eigvecs, Vt[idx][a]
  __shared__ double USw[2][64];                     // U[:, :k]*S[:k] (l x 4)
  __shared__ double evals[2][16];
  __shared__ int dL[2][NS], dR[2][NS];
  __shared__ double lz[2];
  __shared__ double vbuf[2][16];

  float (*A)[1024] = Ash[team];
  float* tmp = Tmp[team];
  float* tsh = Tsh[team];
  double* rw = Rw[team];
  double* gw = Gw[team];
  double* vt = Vt[team];
  double* usw = USw[team];
  double* ev = evals[team];
  int* dl = dL[team];
  int* dr = dR[team];

  double logZ = 0.0;

  // ---- init boundary row (bot: row 0, down=0; top: row 9, up=0) ----
  {
    int row0 = team ? 9 : 0;
    for (int j = 0; j < NS; ++j) {
      int p = xs[row0 * 10 + j];
      const float* tp = peps + ((size_t)(row0 * 10 + j) * 2 + p) * 256;
      ((float4*)tsh)[lane] = ((const float4*)tp)[lane];
      __syncthreads();
      int lgLt = (j == 0) ? 0 : 2, lgRt = (j == 9) ? 0 : 2;
      int Lt = 1 << lgLt, Rt = 1 << lgRt;
      int n = Lt * Rt * 4;
      if (lane < n) {
        int ui = lane & 3, h = lane >> 2;
        int ri = h & (Rt - 1), li = h >> lgRt;
        // bot: B[l,r,u] = T[u,r,0,l]; top: B[l,r,d] = T[0,r,d,l]
        float val = team ? tsh[ri * 16 + ui * 4 + li]
                         : tsh[ui * 64 + ri * 16 + li];
        A[j][lane] = val;
      }
      if (lane == 0) { dl[j] = Lt; dr[j] = Rt; }
      __syncthreads();
    }
  }

  // ---- 4 rounds of absorb + compress ----
  for (int it = 0; it < 4; ++it) {
    int row = team ? (8 - it) : (1 + it);

    // absorb row into MPS
    for (int j = 0; j < NS; ++j) {
      int p = xs[row * 10 + j];
      const float* tp = peps + ((size_t)(row * 10 + j) * 2 + p) * 256;
      ((float4*)tsh)[lane] = ((const float4*)tp)[lane];
      int l = dl[j], r = dr[j];
      int nb = l * r * 4;
      for (int o = lane; o < nb; o += 64) tmp[o] = A[j][o];
      __syncthreads();
      int lgLt = (j == 0) ? 0 : 2, lgRt = (j == 9) ? 0 : 2;
      int lp = l << lgLt, rp = r << lgRt;
      int lgrp = 31 - __clz(rp);
      int n = lp * rp * 4;
      for (int o = lane; o < n; o += 64) {
        int U = o & 3;
        int h = o >> 2;
        int ro = h & (rp - 1), lo = h >> lgrp;
        int li = lo >> lgLt, Li = lo & ((1 << lgLt) - 1);
        int ri = ro >> lgRt, Ri = ro & ((1 << lgRt) - 1);
        double acc = 0.0;
#pragma unroll
        for (int w = 0; w < 4; ++w) {
          float b = tmp[(li * r + ri) * 4 + w];
          // bot: T[U,R,w,L]; top: T[w,R,D,L] (U plays D)
          float t3 = team ? tsh[w * 64 + Ri * 16 + U * 4 + Li]
                          : tsh[U * 64 + Ri * 16 + w * 4 + Li];
          acc += (double)b * (double)t3;
        }
        A[j][o] = (float)acc;
      }
      if (lane == 0) { dl[j] = lp; dr[j] = rp; }
      __syncthreads();
    }

    // ---- QR sweep left->right (MGS in registers, lane = row of M) ----
    for (int j = 0; j < NS - 1; ++j) {
      int l = dl[j], r = dr[j];
      int rows = l * 4, cols = r;
      int kq = rows < cols ? rows : cols;
      // (no rw zero-fill: MGS writes every entry the R-multiply reads)
      double m[16];
      int li = lane >> 2, ui = lane & 3;
      bool act = lane < rows;
#pragma unroll
      for (int c = 0; c < 16; ++c)
        m[c] = (act && c < cols) ? (double)A[j][(li * r + c) * 4 + ui] : 0.0;
      __syncthreads();
#pragma unroll
      for (int c = 0; c < 16; ++c) {
        if (c < kq) {
          double rawd[16];
          // raw dots vs the UNNORMALIZED pivot -> all wsums independent
#pragma unroll
          for (int c2 = c; c2 < 16; ++c2)
            if (c2 < cols) rawd[c2] = wsum64(m[c] * m[c2]);
          double nrm = sqrt(rawd[c]);
          double inv = (nrm > 1e-150) ? 1.0 / nrm : 0.0;
          m[c] *= inv;
          if (lane == 0) rw[c * 16 + c] = nrm;
#pragma unroll
          for (int c2 = c + 1; c2 < 16; ++c2) {
            if (c2 < cols) {
              double dt = rawd[c2] * inv;   // = <q_c, m_c2>
              m[c2] -= dt * m[c];           // m[c] now normalized
              if (lane == 0) rw[c * 16 + c2] = dt;
            }
          }
        }
      }
      if (act) {
#pragma unroll
        for (int c = 0; c < 16; ++c)
          if (c < kq) A[j][(li * kq + c) * 4 + ui] = (float)m[c];
      }
      if (lane == 0) dr[j] = kq;
      __syncthreads();
      // mps[j+1] = R @ mps[j+1]
      int r2 = dr[j + 1];
      int ne = cols * r2 * 4;
      for (int o = lane; o < ne; o += 64) tmp[o] = A[j + 1][o];
      __syncthreads();
      int lgr2 = 31 - __clz(r2);
      int nout = kq * r2 * 4;
      for (int o = lane; o < nout; o += 64) {
        int u2 = o & 3;
        int h = o >> 2;
        int s = h & (r2 - 1), ki = h >> lgr2;
        double acc = 0.0;
        for (int c = ki; c < cols; ++c)  // R upper-triangular
          acc += rw[ki * 16 + c] * (double)tmp[(c * r2 + s) * 4 + u2];
        A[j + 1][o] = (float)acc;
      }
      if (lane == 0) dl[j + 1] = kq;
      __syncthreads();
    }

    // ---- SVD sweep right->left with chi=4 truncation ----
    for (int j = NS - 1; j >= 1; --j) {
      int l = dl[j], r = dr[j], ru = r * 4;
      int mdim = l < ru ? l : ru;
      int k = mdim < 4 ? mdim : 4;
      bool caseA = (l <= ru);
      int d = caseA ? l : ru;
      for (int o = lane; o < 256; o += 64) gw[o] = 0.0;
      __syncthreads();
      if (caseA) {  // G = M M^T (l x l)
        int lgl = 31 - __clz(l);
        for (int idx = lane; idx < l * l; idx += 64) {
          int a = idx >> lgl, b = idx & (l - 1);
          double acc = 0.0;
          for (int t2 = 0; t2 < ru; ++t2)
            acc += (double)A[j][a * ru + t2] * (double)A[j][b * ru + t2];
          gw[a * 16 + b] = acc;
        }
      } else {      // G = M^T M (ru x ru)
        int lgru = 31 - __clz(ru);
        for (int idx = lane; idx < ru * ru; idx += 64) {
          int a = idx >> lgru, b = idx & (ru - 1);
          double acc = 0.0;
          for (int t2 = 0; t2 < l; ++t2)
            acc += (double)A[j][t2 * ru + a] * (double)A[j][t2 * ru + b];
          gw[a * 16 + b] = acc;
        }
      }
      __syncthreads();
      if (d > 4) jacobi_sym_x<15>(gw, vt, ev, lane, 8);
      else       jacobi_sym_x<3>(gw, vt, ev, lane, 5);
      __syncthreads();
      // top-k eigenpairs (redundant per lane)
      int idxs[4]; double sv[4];
      idxs[0] = idxs[1] = idxs[2] = idxs[3] = 0;
      sv[0] = sv[1] = sv[2] = sv[3] = 0.0;
      unsigned msk = 0;
#pragma unroll
      for (int t2 = 0; t2 < 4; ++t2) {
        if (t2 < k) {
          double best = -1.0; int bi = 0;
          for (int a = 0; a < 16; ++a) {
            double ea = ev[a];
            bool ok = !((msk >> a) & 1) && (ea > best);
            best = ok ? ea : best;
            bi = ok ? a : bi;
          }
          msk |= (1u << bi);
          idxs[t2] = bi;
          sv[t2] = sqrt(best > 0.0 ? best : 0.0);
        }
      }
      // Vh rows (regs) + US (LDS) computed BEFORE overwriting A[j]
      double vh[4] = {0.0, 0.0, 0.0, 0.0};
      if (caseA) {
        if (lane < ru) {
#pragma unroll
          for (int t2 = 0; t2 < 4; ++t2) if (t2 < k) {
            double acc = 0.0;
            for (int a = 0; a < l; ++a)
              acc += vt[idxs[t2] * 16 + a] * (double)A[j][a * ru + lane];
            double invs = sv[t2] > 1e-150 ? 1.0 / sv[t2] : 0.0;
            vh[t2] = acc * invs;
          }
        }
        if (lane < l) {
#pragma unroll
          for (int t2 = 0; t2 < 4; ++t2)
            usw[lane * 4 + t2] =
                (t2 < k) ? vt[idxs[t2] * 16 + lane] * sv[t2] : 0.0;
        }
      } else {
        if (lane < ru) {
#pragma unroll
          for (int t2 = 0; t2 < 4; ++t2)
            if (t2 < k) vh[t2] = vt[idxs[t2] * 16 + lane];
        }
        if (lane < l) {
#pragma unroll
          for (int t2 = 0; t2 < 4; ++t2) {
            double acc = 0.0;
            if (t2 < k)
              for (int q2 = 0; q2 < ru; ++q2)
                acc += (double)A[j][lane * ru + q2] * vt[idxs[t2] * 16 + q2];
            usw[lane * 4 + t2] = acc;
          }
        }
      }
      __syncthreads();
      if (lane < ru) {
#pragma unroll
        for (int t2 = 0; t2 < 4; ++t2)
          if (t2 < k) A[j][t2 * ru + lane] = (float)vh[t2];
      }
      if (lane == 0) dl[j] = k;
      __syncthreads();
      // mps[j-1] <- mps[j-1] @ US
      int l1 = dl[j - 1], r1 = dr[j - 1];  // r1 == l
      int ne = l1 * r1 * 4;
      for (int o = lane; o < ne; o += 64) tmp[o] = A[j - 1][o];
      __syncthreads();
      int lgk = 31 - __clz(k);
      int nout = l1 * k * 4;
      for (int o = lane; o < nout; o += 64) {
        int u2 = o & 3;
        int h = o >> 2;
        int ki = h & (k - 1), li2 = h >> lgk;
        double acc = 0.0;
        for (int m2 = 0; m2 < l; ++m2)
          acc += (double)tmp[(li2 * l + m2) * 4 + u2] * usw[m2 * 4 + ki];
        A[j - 1][o] = (float)acc;
      }
      if (lane == 0) dr[j - 1] = k;
      __syncthreads();
    }

    // ---- strip norms (equalize_norms=1.0) ----
    for (int j = 0; j < NS; ++j) {
      int nels = dl[j] * dr[j] * 4;
      double part = 0.0;
      for (int o = lane; o < nels; o += 64) {
        double x = A[j][o];
        part += x * x;
      }
      double nrm = sqrt(wsum64(part));
      double safe = nrm > 0.0 ? nrm : 1.0;
      float invs = (float)(1.0 / safe);
      for (int o = lane; o < nels; o += 64) A[j][o] *= invs;
      logZ += log(safe);
      __syncthreads();
    }
  }

  // ---- final contraction of bot & top MPS ----
  if (lane == 0) lz[team] = logZ;
  if (tid < 16) vbuf[0][tid] = (tid == 0) ? 1.0 : 0.0;
  __syncthreads();
  int cur = 0;
  for (int j = 0; j < NS; ++j) {
    if (tid < 16) {
      int adim = dL[0][j], pdim = dR[0][j];  // identical for both teams
      int pp = tid >> 2, qq = tid & 3;
      double acc = 0.0;
      if (pp < pdim && qq < pdim) {
        for (int a = 0; a < adim; ++a)
          for (int b = 0; b < adim; ++b) {
            double vab = vbuf[cur][a * 4 + b];
            double s2 = 0.0;
#pragma unroll
            for (int u = 0; u < 4; ++u)
              s2 += (double)Ash[0][j][(a * pdim + pp) * 4 + u] *
                    (double)Ash[1][j][(b * pdim + qq) * 4 + u];
            acc += vab * s2;
          }
      }
      vbuf[cur ^ 1][tid] = acc;
    }
    __syncthreads();
    cur ^= 1;
  }
  if (tid == 0) out[0] = (float)(vbuf[cur][0] * exp(lz[0] + lz[1]));
}

extern "C" void kernel_launch(void* const* d_in, const int* in_sizes, int n_in,
                              void* d_out, int out_size, void* d_ws, size_t ws_size,
                              hipStream_t stream) {
  const float* peps = (const float*)d_in[0];  // (10,10,2,4,4,4,4) fp32
  const int* xs = (const int*)d_in[1];        // (100,) int32
  float* out = (float*)d_out;                 // scalar fp32
  (void)in_sizes; (void)n_in; (void)out_size; (void)d_ws; (void)ws_size;
  amp_kernel<<<dim3(1), dim3(128), 0, stream>>>(peps, xs, out);
}

// Round 12
// 3436.931 us; speedup vs baseline: 1.0795x; 1.0795x over previous
//
#include <hip/hip_runtime.h>
#include <math.h>

// PEPS amplitude via boundary-MPS contraction, fully fused in one kernel.
// Lx=Ly=10, PHYS=2, D=4, CHI=4. Two teams (2 waves): team0 = bottom half,
// team1 = top half (identical shape sequences -> lockstep barriers).
// Decompositions (MGS-QR, Gram + XOR-scheduled parallel Jacobi) in fp64.
// Accumulation loops use float4 loads + 4 independent partial sums to
// overlap LDS latency (runtime trip counts defeat compiler unrolling).

#define NS 10

__device__ __forceinline__ double shfl_d(double x, int src) {
  union { double d; int i[2]; } u;
  u.d = x;
  u.i[0] = __shfl(u.i[0], src, 64);
  u.i[1] = __shfl(u.i[1], src, 64);
  return u.d;
}
__device__ __forceinline__ double shflx_d(double x, int m) {
  union { double d; int i[2]; } u;
  u.d = x;
  u.i[0] = __shfl_xor(u.i[0], m, 64);
  u.i[1] = __shfl_xor(u.i[1], m, 64);
  return u.d;
}
__device__ __forceinline__ double wsum64(double x) {
#pragma unroll
  for (int o = 1; o < 64; o <<= 1) x += shflx_d(x, o);
  return x;
}
#define SEL4(a, k) ((k) == 1 ? (a)[1] : (k) == 2 ? (a)[2] : (k) == 3 ? (a)[3] : (a)[0])

// Two-sided parallel Jacobi eigensolver on a zero-padded 16x16 symmetric PSD
// matrix, XOR (hypercube) pair schedule: round d pairs {x, x^d}.
// Rotation params in fp64 (fp32 was tried r10: its ~1e-7 angle error floors
// off-norm ABOVE any tight threshold -> early exit never fires -> net LOSS;
// rounds are shuffle-dominated so fp64 arith is affordable).
// Layout: lane = i*4 + j4 holds G[i][4*j4..4*j4+3] and Vt likewise.
// No barriers inside (per-team early exit is safe).
template <int NDMAX>
__device__ void jacobi_sym_x(const double* gw, double* vtw, double* ev,
                             int lane, int maxsweep) {
  const int i = lane >> 2, j4 = lane & 3;
  double g[4], v[4];
#pragma unroll
  for (int cc = 0; cc < 4; ++cc) {
    g[cc] = gw[i * 16 + j4 * 4 + cc];
    v[cc] = (i == j4 * 4 + cc) ? 1.0 : 0.0;
  }
  double thr = 0.0;
  for (int sw = 0; sw < maxsweep; ++sw) {
    double off = 0.0, dsq = 0.0;
#pragma unroll
    for (int cc = 0; cc < 4; ++cc) {
      double gv = g[cc];
      if (j4 * 4 + cc == i) dsq += gv * gv; else off += gv * gv;
    }
    if (sw == 0) {
      // trace(G^2) is invariant under the similarity -> compute scale once
      thr = wsum64(off + dsq) * 1e-16;
    } else {
      if (wsum64(off) <= thr) break;  // uniform across wave
    }
#pragma unroll
    for (int d = 1; d <= NDMAX; ++d) {
      const int hb = d >= 8 ? 3 : d >= 4 ? 2 : d >= 2 ? 1 : 0;
      // my row pair {i, i^d}: t1=G[i][i], t2=G[i^d][i^d], t3=G[i][i^d]
      double dsel = SEL4(g, i & 3);                 // provider: G[row][row]
      double psel = SEL4(g, (i & 3) ^ (d & 3));     // provider: G[row][row^d]
      double t1 = shfl_d(dsel, (i << 2) + (i >> 2));
      double t3 = shfl_d(psel, (i << 2) + ((i ^ d) >> 2));
      double t2 = shfl_d(dsel, ((i ^ d) << 2) + ((i ^ d) >> 2));
      bool iq = ((i >> hb) & 1) != 0;               // I'm Q-side of my pair
      double th = iq ? (t1 - t2) : (t2 - t1);       // aqq - app
      double ph = 2.0 * t3;
      double den = fabs(th) + sqrt(th * th + ph * ph);
      double t = (den > 0.0) ? copysign(1.0, th) * ph / den : 0.0;
      double cr = rsqrt(1.0 + t * t);
      double sr = t * cr;
      // column phase: col x needs (c,s) of pair {x,x^d} and G[i][x^d]
      double oc[4], os[4], oth[4];
#pragma unroll
      for (int cc = 0; cc < 4; ++cc) {
        int col = (j4 << 2) + cc;
        int asrc = (col << 2) + (col >> 2);         // a lane of row `col`
        oc[cc] = shfl_d(cr, asrc);
        os[cc] = shfl_d(sr, asrc);
        oth[cc] = (d >> 2) ? shflx_d(g[cc ^ (d & 3)], d >> 2)
                           : g[cc ^ (d & 3)];
      }
#pragma unroll
      for (int cc = 0; cc < 4; ++cc) {
        int col = (j4 << 2) + cc;
        double sg = ((col >> hb) & 1) ? os[cc] : -os[cc];  // P side: -s
        g[cc] = oc[cc] * g[cc] + sg * oth[cc];
      }
      // row phase (+ Vt): partner row lane = lane ^ (4d)
      double og[4], ov[4];
#pragma unroll
      for (int cc = 0; cc < 4; ++cc) og[cc] = shflx_d(g[cc], d << 2);
#pragma unroll
      for (int cc = 0; cc < 4; ++cc) ov[cc] = shflx_d(v[cc], d << 2);
      double sg2 = iq ? sr : -sr;
#pragma unroll
      for (int cc = 0; cc < 4; ++cc) {
        g[cc] = cr * g[cc] + sg2 * og[cc];
        v[cc] = cr * v[cc] + sg2 * ov[cc];
      }
    }
  }
#pragma unroll
  for (int cc = 0; cc < 4; ++cc) vtw[i * 16 + j4 * 4 + cc] = v[cc];
  if ((i >> 2) == j4) ev[i] = SEL4(g, i & 3);
}

__global__ __launch_bounds__(128, 1)
void amp_kernel(const float* __restrict__ peps, const int* __restrict__ xs,
                float* __restrict__ out) {
  const int tid = threadIdx.x;
  const int team = tid >> 6;      // 0 = bottom half, 1 = top half
  const int lane = tid & 63;

  __shared__ __align__(16) float Ash[2][NS][1024];  // MPS tensors (l,r,4)
  __shared__ __align__(16) float Tmp[2][1024];      // staging
  __shared__ __align__(16) float Tsh[2][256];       // site tensor T (4,4,4,4)
  __shared__ double Rw[2][256];                     // QR R (16x16)
  __shared__ double Gw[2][256];                     // Gram (16x16, zero-pad)
  __shared__ double Vt[2][256];                     // eigvecs, Vt[idx][a]
  __shared__ double USw[2][64];                     // U[:, :k]*S[:k] (l x 4)
  __shared__ double evals[2][16];
  __shared__ int dL[2][NS], dR[2][NS];
  __shared__ double lz[2];
  __shared__ double vbuf[2][16];

  float (*A)[1024] = Ash[team];
  float* tmp = Tmp[team];
  float* tsh = Tsh[team];
  double* rw = Rw[team];
  double* gw = Gw[team];
  double* vt = Vt[team];
  double* usw = USw[team];
  double* ev = evals[team];
  int* dl = dL[team];
  int* dr = dR[team];

  double logZ = 0.0;

  // ---- init boundary row (bot: row 0, down=0; top: row 9, up=0) ----
  {
    int row0 = team ? 9 : 0;
    for (int j = 0; j < NS; ++j) {
      int p = xs[row0 * 10 + j];
      const float* tp = peps + ((size_t)(row0 * 10 + j) * 2 + p) * 256;
      ((float4*)tsh)[lane] = ((const float4*)tp)[lane];
      __syncthreads();
      int lgLt = (j == 0) ? 0 : 2, lgRt = (j == 9) ? 0 : 2;
      int Lt = 1 << lgLt, Rt = 1 << lgRt;
      int n = Lt * Rt * 4;
      if (lane < n) {
        int ui = lane & 3, h = lane >> 2;
        int ri = h & (Rt - 1), li = h >> lgRt;
        // bot: B[l,r,u] = T[u,r,0,l]; top: B[l,r,d] = T[0,r,d,l]
        float val = team ? tsh[ri * 16 + ui * 4 + li]
                         : tsh[ui * 64 + ri * 16 + li];
        A[j][lane] = val;
      }
      if (lane == 0) { dl[j] = Lt; dr[j] = Rt; }
      __syncthreads();
    }
  }

  // ---- 4 rounds of absorb + compress ----
  for (int it = 0; it < 4; ++it) {
    int row = team ? (8 - it) : (1 + it);

    // absorb row into MPS
    for (int j = 0; j < NS; ++j) {
      int p = xs[row * 10 + j];
      const float* tp = peps + ((size_t)(row * 10 + j) * 2 + p) * 256;
      ((float4*)tsh)[lane] = ((const float4*)tp)[lane];
      int l = dl[j], r = dr[j];
      int nb4 = (l * r * 4) >> 2;
      for (int o = lane; o < nb4; o += 64)
        ((float4*)tmp)[o] = ((const float4*)A[j])[o];
      __syncthreads();
      int lgLt = (j == 0) ? 0 : 2, lgRt = (j == 9) ? 0 : 2;
      int lp = l << lgLt, rp = r << lgRt;
      int lgrp = 31 - __clz(rp);
      int n = lp * rp * 4;
      for (int o = lane; o < n; o += 64) {
        int U = o & 3;
        int h = o >> 2;
        int ro = h & (rp - 1), lo = h >> lgrp;
        int li = lo >> lgLt, Li = lo & ((1 << lgLt) - 1);
        int ri = ro >> lgRt, Ri = ro & ((1 << lgRt) - 1);
        // B[li,ri,w] as one float4; 4 independent tsh loads
        const float4 bf = *(const float4*)&tmp[(li * r + ri) * 4];
        double acc;
        if (team) {  // top: T[w,R,D,L], U plays D
          const float* tb = &tsh[Ri * 16 + U * 4 + Li];
          acc = (double)bf.x * tb[0] + (double)bf.y * tb[64] +
                (double)bf.z * tb[128] + (double)bf.w * tb[192];
        } else {     // bot: T[U,R,w,L]
          const float* tb = &tsh[U * 64 + Ri * 16 + Li];
          acc = (double)bf.x * tb[0] + (double)bf.y * tb[4] +
                (double)bf.z * tb[8] + (double)bf.w * tb[12];
        }
        A[j][o] = (float)acc;
      }
      if (lane == 0) { dl[j] = lp; dr[j] = rp; }
      __syncthreads();
    }

    // ---- QR sweep left->right (MGS in registers, lane = row of M) ----
    for (int j = 0; j < NS - 1; ++j) {
      int l = dl[j], r = dr[j];
      int rows = l * 4, cols = r;
      int kq = rows < cols ? rows : cols;
      // (no rw zero-fill: MGS writes every entry the R-multiply reads)
      double m[16];
      int li = lane >> 2, ui = lane & 3;
      bool act = lane < rows;
#pragma unroll
      for (int c = 0; c < 16; ++c)
        m[c] = (act && c < cols) ? (double)A[j][(li * r + c) * 4 + ui] : 0.0;
      __syncthreads();
#pragma unroll
      for (int c = 0; c < 16; ++c) {
        if (c < kq) {
          double rawd[16];
          // raw dots vs the UNNORMALIZED pivot -> all wsums independent
#pragma unroll
          for (int c2 = c; c2 < 16; ++c2)
            if (c2 < cols) rawd[c2] = wsum64(m[c] * m[c2]);
          double nrm = sqrt(rawd[c]);
          double inv = (nrm > 1e-150) ? 1.0 / nrm : 0.0;
          m[c] *= inv;
          if (lane == 0) rw[c * 16 + c] = nrm;
#pragma unroll
          for (int c2 = c + 1; c2 < 16; ++c2) {
            if (c2 < cols) {
              double dt = rawd[c2] * inv;   // = <q_c, m_c2>
              m[c2] -= dt * m[c];           // m[c] now normalized
              if (lane == 0) rw[c * 16 + c2] = dt;
            }
          }
        }
      }
      if (act) {
#pragma unroll
        for (int c = 0; c < 16; ++c)
          if (c < kq) A[j][(li * kq + c) * 4 + ui] = (float)m[c];
      }
      if (lane == 0) dr[j] = kq;
      __syncthreads();
      // mps[j+1] = R @ mps[j+1]
      int r2 = dr[j + 1];
      int ne4 = (cols * r2 * 4) >> 2;
      for (int o = lane; o < ne4; o += 64)
        ((float4*)tmp)[o] = ((const float4*)A[j + 1])[o];
      __syncthreads();
      int lgr2 = 31 - __clz(r2);
      int nout = kq * r2 * 4;
      int stride = r2 * 4;
      for (int o = lane; o < nout; o += 64) {
        int u2 = o & 3;
        int h = o >> 2;
        int s = h & (r2 - 1), ki = h >> lgr2;
        const double* rrow = &rw[ki * 16];
        const float* tcol = &tmp[s * 4 + u2];
        double s0 = 0.0, s1 = 0.0, s2 = 0.0, s3 = 0.0;
        int c = ki;                       // R upper-triangular
        for (; c + 4 <= cols; c += 4) {
          s0 += rrow[c + 0] * (double)tcol[(c + 0) * stride];
          s1 += rrow[c + 1] * (double)tcol[(c + 1) * stride];
          s2 += rrow[c + 2] * (double)tcol[(c + 2) * stride];
          s3 += rrow[c + 3] * (double)tcol[(c + 3) * stride];
        }
        for (; c < cols; ++c) s0 += rrow[c] * (double)tcol[c * stride];
        A[j + 1][o] = (float)((s0 + s1) + (s2 + s3));
      }
      if (lane == 0) dl[j + 1] = kq;
      __syncthreads();
    }

    // ---- SVD sweep right->left with chi=4 truncation ----
    for (int j = NS - 1; j >= 1; --j) {
      int l = dl[j], r = dr[j], ru = r * 4;
      int mdim = l < ru ? l : ru;
      int k = mdim < 4 ? mdim : 4;
      bool caseA = (l <= ru);
      int d = caseA ? l : ru;
      for (int o = lane; o < 256; o += 64) gw[o] = 0.0;
      __syncthreads();
      if (caseA) {  // G = M M^T (l x l), inner contiguous over ru -> float4
        int lgl = 31 - __clz(l);
        int nq = ru >> 2;
        for (int idx = lane; idx < l * l; idx += 64) {
          int a = idx >> lgl, b = idx & (l - 1);
          const float4* pa = (const float4*)&A[j][a * ru];
          const float4* pb = (const float4*)&A[j][b * ru];
          double s0 = 0.0, s1 = 0.0, s2 = 0.0, s3 = 0.0;
          for (int q = 0; q < nq; ++q) {
            float4 fa = pa[q], fb = pb[q];
            s0 += (double)fa.x * fb.x;
            s1 += (double)fa.y * fb.y;
            s2 += (double)fa.z * fb.z;
            s3 += (double)fa.w * fb.w;
          }
          gw[a * 16 + b] = (s0 + s1) + (s2 + s3);
        }
      } else {      // G = M^T M (ru x ru), inner over l (stride ru)
        int lgru = 31 - __clz(ru);
        for (int idx = lane; idx < ru * ru; idx += 64) {
          int a = idx >> lgru, b = idx & (ru - 1);
          double s0 = 0.0, s1 = 0.0, s2 = 0.0, s3 = 0.0;
          int t2 = 0;
          for (; t2 + 4 <= l; t2 += 4) {
            s0 += (double)A[j][(t2 + 0) * ru + a] * A[j][(t2 + 0) * ru + b];
            s1 += (double)A[j][(t2 + 1) * ru + a] * A[j][(t2 + 1) * ru + b];
            s2 += (double)A[j][(t2 + 2) * ru + a] * A[j][(t2 + 2) * ru + b];
            s3 += (double)A[j][(t2 + 3) * ru + a] * A[j][(t2 + 3) * ru + b];
          }
          for (; t2 < l; ++t2)
            s0 += (double)A[j][t2 * ru + a] * A[j][t2 * ru + b];
          gw[a * 16 + b] = (s0 + s1) + (s2 + s3);
        }
      }
      __syncthreads();
      if (d > 4) jacobi_sym_x<15>(gw, vt, ev, lane, 8);
      else       jacobi_sym_x<3>(gw, vt, ev, lane, 5);
      __syncthreads();
      // top-k eigenpairs: ev -> registers (16 independent LDS reads),
      // fully unrolled selection (compile-time indices, no scratch)
      double evr[16];
#pragma unroll
      for (int a = 0; a < 16; ++a) evr[a] = ev[a];
      int idxs[4]; double sv[4];
      idxs[0] = idxs[1] = idxs[2] = idxs[3] = 0;
      sv[0] = sv[1] = sv[2] = sv[3] = 0.0;
      unsigned msk = 0;
#pragma unroll
      for (int t2 = 0; t2 < 4; ++t2) {
        if (t2 < k) {
          double best = -1.0; int bi = 0;
#pragma unroll
          for (int a = 0; a < 16; ++a) {
            double ea = evr[a];
            bool ok = !((msk >> a) & 1) && (ea > best);
            best = ok ? ea : best;
            bi = ok ? a : bi;
          }
          msk |= (1u << bi);
          idxs[t2] = bi;
          sv[t2] = sqrt(best > 0.0 ? best : 0.0);
        }
      }
      // Vh rows (regs) + US (LDS) computed BEFORE overwriting A[j]
      double vh[4] = {0.0, 0.0, 0.0, 0.0};
      if (caseA) {
        if (lane < ru) {
#pragma unroll
          for (int t2 = 0; t2 < 4; ++t2) if (t2 < k) {
            const double* vrow = &vt[idxs[t2] * 16];
            double s0 = 0.0, s1 = 0.0, s2 = 0.0, s3 = 0.0;
            int a = 0;
            for (; a + 4 <= l; a += 4) {
              s0 += vrow[a + 0] * (double)A[j][(a + 0) * ru + lane];
              s1 += vrow[a + 1] * (double)A[j][(a + 1) * ru + lane];
              s2 += vrow[a + 2] * (double)A[j][(a + 2) * ru + lane];
              s3 += vrow[a + 3] * (double)A[j][(a + 3) * ru + lane];
            }
            for (; a < l; ++a) s0 += vrow[a] * (double)A[j][a * ru + lane];
            double acc = (s0 + s1) + (s2 + s3);
            double invs = sv[t2] > 1e-150 ? 1.0 / sv[t2] : 0.0;
            vh[t2] = acc * invs;
          }
        }
        if (lane < l) {
#pragma unroll
          for (int t2 = 0; t2 < 4; ++t2)
            usw[lane * 4 + t2] =
                (t2 < k) ? vt[idxs[t2] * 16 + lane] * sv[t2] : 0.0;
        }
      } else {
        if (lane < ru) {
#pragma unroll
          for (int t2 = 0; t2 < 4; ++t2)
            if (t2 < k) vh[t2] = vt[idxs[t2] * 16 + lane];
        }
        if (lane < l) {
#pragma unroll
          for (int t2 = 0; t2 < 4; ++t2) {
            double acc = 0.0;
            if (t2 < k) {
              const double* vrow = &vt[idxs[t2] * 16];
              const float* arow = &A[j][lane * ru];
              double s0 = 0.0, s1 = 0.0, s2 = 0.0, s3 = 0.0;
              int q2 = 0;
              for (; q2 + 4 <= ru; q2 += 4) {
                s0 += (double)arow[q2 + 0] * vrow[q2 + 0];
                s1 += (double)arow[q2 + 1] * vrow[q2 + 1];
                s2 += (double)arow[q2 + 2] * vrow[q2 + 2];
                s3 += (double)arow[q2 + 3] * vrow[q2 + 3];
              }
              for (; q2 < ru; ++q2) s0 += (double)arow[q2] * vrow[q2];
              acc = (s0 + s1) + (s2 + s3);
            }
            usw[lane * 4 + t2] = acc;
          }
        }
      }
      __syncthreads();
      if (lane < ru) {
#pragma unroll
        for (int t2 = 0; t2 < 4; ++t2)
          if (t2 < k) A[j][t2 * ru + lane] = (float)vh[t2];
      }
      if (lane == 0) dl[j] = k;
      __syncthreads();
      // mps[j-1] <- mps[j-1] @ US
      int l1 = dl[j - 1], r1 = dr[j - 1];  // r1 == l
      int ne4 = (l1 * r1 * 4) >> 2;
      for (int o = lane; o < ne4; o += 64)
        ((float4*)tmp)[o] = ((const float4*)A[j - 1])[o];
      __syncthreads();
      int lgk = 31 - __clz(k);
      int nout = l1 * k * 4;
      for (int o = lane; o < nout; o += 64) {
        int u2 = o & 3;
        int h = o >> 2;
        int ki = h & (k - 1), li2 = h >> lgk;
        const float* trow = &tmp[li2 * l * 4 + u2];
        const double* ucol = &usw[ki];
        double s0 = 0.0, s1 = 0.0, s2 = 0.0, s3 = 0.0;
        int m2 = 0;
        for (; m2 + 4 <= l; m2 += 4) {
          s0 += (double)trow[(m2 + 0) * 4] * ucol[(m2 + 0) * 4];
          s1 += (double)trow[(m2 + 1) * 4] * ucol[(m2 + 1) * 4];
          s2 += (double)trow[(m2 + 2) * 4] * ucol[(m2 + 2) * 4];
          s3 += (double)trow[(m2 + 3) * 4] * ucol[(m2 + 3) * 4];
        }
        for (; m2 < l; ++m2) s0 += (double)trow[m2 * 4] * ucol[m2 * 4];
        A[j - 1][o] = (float)((s0 + s1) + (s2 + s3));
      }
      if (lane == 0) dr[j - 1] = k;
      __syncthreads();
    }

    // ---- strip norms (equalize_norms=1.0) ----
    for (int j = 0; j < NS; ++j) {
      int n4 = (dl[j] * dr[j] * 4) >> 2;
      double part = 0.0;
      for (int o = lane; o < n4; o += 64) {
        float4 v = ((const float4*)A[j])[o];
        part += (double)v.x * v.x + (double)v.y * v.y +
                (double)v.z * v.z + (double)v.w * v.w;
      }
      double nrm = sqrt(wsum64(part));
      double safe = nrm > 0.0 ? nrm : 1.0;
      float invs = (float)(1.0 / safe);
      for (int o = lane; o < n4; o += 64) {
        float4 v = ((float4*)A[j])[o];
        v.x *= invs; v.y *= invs; v.z *= invs; v.w *= invs;
        ((float4*)A[j])[o] = v;
      }
      logZ += log(safe);
      __syncthreads();
    }
  }

  // ---- final contraction of bot & top MPS ----
  if (lane == 0) lz[team] = logZ;
  if (tid < 16) vbuf[0][tid] = (tid == 0) ? 1.0 : 0.0;
  __syncthreads();
  int cur = 0;
  for (int j = 0; j < NS; ++j) {
    if (tid < 16) {
      int adim = dL[0][j], pdim = dR[0][j];  // identical for both teams
      int pp = tid >> 2, qq = tid & 3;
      double acc = 0.0;
      if (pp < pdim && qq < pdim) {
        for (int a = 0; a < adim; ++a)
          for (int b = 0; b < adim; ++b) {
            double vab = vbuf[cur][a * 4 + b];
            double s2 = 0.0;
#pragma unroll
            for (int u = 0; u < 4; ++u)
              s2 += (double)Ash[0][j][(a * pdim + pp) * 4 + u] *
                    (double)Ash[1][j][(b * pdim + qq) * 4 + u];
            acc += vab * s2;
          }
      }
      vbuf[cur ^ 1][tid] = acc;
    }
    __syncthreads();
    cur ^= 1;
  }
  if (tid == 0) out[0] = (float)(vbuf[cur][0] * exp(lz[0] + lz[1]));
}

extern "C" void kernel_launch(void* const* d_in, const int* in_sizes, int n_in,
                              void* d_out, int out_size, void* d_ws, size_t ws_size,
                              hipStream_t stream) {
  const float* peps = (const float*)d_in[0];  // (10,10,2,4,4,4,4) fp32
  const int* xs = (const int*)d_in[1];        // (100,) int32
  float* out = (float*)d_out;                 // scalar fp32
  (void)in_sizes; (void)n_in; (void)out_size; (void)d_ws; (void)ws_size;
  amp_kernel<<<dim3(1), dim3(128), 0, stream>>>(peps, xs, out);
}